// Round 5
// baseline (33.659 us; speedup 1.0000x reference)
//
#include <hip/hip_runtime.h>
#include <math.h>
#include <stdint.h>

#define BATCH   8192
#define NI      8
#define NM      3
#define NROWS   81     // rH = digits of inputs 0..3
#define NL      81     // rL = digits of inputs 4..7
#define NPAIR   41     // ceil(81/2) rule-pairs per rH row
#define HROW    (NPAIR * 9)   // 369 u32 per rH row
#define IL2C    (-0.72134752f)  // -0.5*log2(e)

typedef uint32_t u32;
typedef __fp16 h2 __attribute__((ext_vector_type(2)));

__device__ __forceinline__ h2 pack_h2(float a, float b) {
#if __has_builtin(__builtin_amdgcn_cvt_pkrtz)
    return __builtin_amdgcn_cvt_pkrtz(a, b);
#else
    h2 r; r.x = (__fp16)a; r.y = (__fp16)b; return r;
#endif
}

__device__ __forceinline__ float fdot2(h2 a, h2 b, float c) {
#if __has_builtin(__builtin_amdgcn_fdot2)
    return __builtin_amdgcn_fdot2(a, b, c, false);
#else
    return c + (float)a.x * (float)b.x + (float)a.y * (float)b.y;
#endif
}

__device__ __forceinline__ h2 as_h2(u32 v) { return __builtin_bit_cast(h2, v); }

__device__ __forceinline__ float sel3(const float* a, int i) {
    return (i == 0) ? a[0] : ((i == 1) ? a[1] : a[2]);
}

// Pack consequents to f16 rule-pairs: H[rH*369 + p*9 + i] = (c[rH*81+2p][i], c[rH*81+2p+1][i])
__global__ __launch_bounds__(256) void sugeno_prep(
    const float* __restrict__ cons,   // [6561][9]
    u32* __restrict__ H)
{
    int t = blockIdx.x * 256 + threadIdx.x;
    if (t >= NROWS * HROW) return;
    int rH  = t / HROW;
    int rem = t - rH * HROW;
    int p   = rem / 9;
    int i   = rem - p * 9;
    int rl0 = 2 * p, rl1 = 2 * p + 1;
    float c0 = cons[(size_t)(rH * NL + rl0) * 9 + i];
    float c1 = (rl1 < NL) ? cons[(size_t)(rH * NL + rl1) * 9 + i] : 0.0f;
    h2 hv; hv.x = (__fp16)c0; hv.y = (__fp16)c1;
    H[t] = __builtin_bit_cast(u32, hv);
}

// partial[rH][b] = sum_rL s'[b, rH*81+rL] * (xb[b] . cons[rH*81+rL])
// where s' = s * 2^{-K(b)}, K(b) = sum_j max_m a_jm  (so max rule strength == 1)
__global__ __launch_bounds__(256, 4) void sugeno_partial(
    const float* __restrict__ x,        // [BATCH][8]
    const float* __restrict__ centers,  // [8][3]
    const float* __restrict__ sigmas,   // [3]
    const u32*   __restrict__ H,        // [81][41][9] packed f16 pairs
    float* __restrict__ partial)        // [81][BATCH]
{
    const int b  = blockIdx.x * 256 + threadIdx.x;
    const int rH = blockIdx.y;          // uniform -> all H addressing is scalar

    const float4* xv = reinterpret_cast<const float4*>(x + (size_t)b * NI);
    float4 xa = xv[0], xb4 = xv[1];
    float xr[NI];
    xr[0]=xa.x; xr[1]=xa.y; xr[2]=xa.z; xr[3]=xa.w;
    xr[4]=xb4.x; xr[5]=xb4.y; xr[6]=xb4.z; xr[7]=xb4.w;

    float il2[NM];
    #pragma unroll
    for (int m = 0; m < NM; ++m) {
        float s = sigmas[m];
        il2[m] = IL2C / (s * s);
    }

    // exp2-domain membership arguments a[j][m] <= 0
    float a[NI][NM];
    #pragma unroll
    for (int j = 0; j < NI; ++j) {
        #pragma unroll
        for (int m = 0; m < NM; ++m) {
            float d = xr[j] - centers[j * NM + m];
            a[j][m] = d * d * il2[m];
        }
    }
    // per-input max argument (log2 of max mu) — scaling exponents
    float K[NI];
    #pragma unroll
    for (int j = 0; j < NI; ++j)
        K[j] = fmaxf(fmaxf(a[j][0], a[j][1]), a[j][2]);

    // digits of rH (uniform)
    const int d0 = rH / 27;
    const int d1 = (rH / 9) % 3;
    const int d2 = (rH / 3) % 3;
    const int d3 = rH % 3;

    // scaled high product in (0,1]
    float argh = (sel3(a[0], d0) - K[0]) + (sel3(a[1], d1) - K[1])
               + (sel3(a[2], d2) - K[2]) + (sel3(a[3], d3) - K[3]);
    float ph = exp2f(argh);

    // scaled mu for inputs 4..7, each in (0,1]
    float mu4[NM], mu5[NM], mu6[NM], mu7[NM];
    #pragma unroll
    for (int m = 0; m < NM; ++m) {
        mu4[m] = exp2f(a[4][m] - K[4]);
        mu5[m] = exp2f(a[5][m] - K[5]);
        mu6[m] = exp2f(a[6][m] - K[6]);
        mu7[m] = exp2f(a[7][m] - K[7]);
    }

    // t27[q] = ph * mu4[q/9?]... : q = rL/3 in [0,27): t27[q] = ph*mu4[q/9]*mu5[(q/3)%3]*mu6[q%3]
    float m45[9];
    #pragma unroll
    for (int p = 0; p < 3; ++p) {
        float pa = ph * mu4[p];
        #pragma unroll
        for (int q = 0; q < 3; ++q) m45[p * 3 + q] = pa * mu5[q];
    }
    float t27[27];
    #pragma unroll
    for (int q = 0; q < 27; ++q)
        t27[q] = m45[q / 3] * mu6[q % 3];

    const u32* __restrict__ Hrow = H + (size_t)rH * HROW;

    float V[9];
    #pragma unroll
    for (int i = 0; i < 9; ++i) V[i] = 0.0f;

    // s'(rL) = t27[rL/3] * mu7[rL%3]; process pairs (2k, 2k+1)
    #pragma unroll
    for (int k = 0; k < NPAIR - 1; ++k) {
        const int r0 = 2 * k, r1 = 2 * k + 1;
        float s0 = t27[r0 / 3] * mu7[r0 % 3];
        float s1 = t27[r1 / 3] * mu7[r1 % 3];
        h2 sp = pack_h2(s0, s1);
        #pragma unroll
        for (int i = 0; i < 9; ++i)
            V[i] = fdot2(sp, as_h2(Hrow[k * 9 + i]), V[i]);
    }
    {   // tail rule rL = 80 (paired with zero)
        float s80 = t27[26] * mu7[2];
        h2 sp = pack_h2(s80, 0.0f);
        #pragma unroll
        for (int i = 0; i < 9; ++i)
            V[i] = fdot2(sp, as_h2(Hrow[(NPAIR - 1) * 9 + i]), V[i]);
    }

    const float numer = V[0]*xr[0] + V[1]*xr[1] + V[2]*xr[2] + V[3]*xr[3]
                      + V[4]*xr[4] + V[5]*xr[5] + V[6]*xr[6] + V[7]*xr[7]
                      + V[8];
    partial[(size_t)rH * BATCH + b] = numer;
}

// out[b] = (sum_rH partial[rH][b]) * 2^K / (S + 1e-6),  S = prod_j sum_m mu (exact f32)
__global__ __launch_bounds__(256) void sugeno_reduce(
    const float* __restrict__ x,
    const float* __restrict__ centers,
    const float* __restrict__ sigmas,
    const float* __restrict__ partial,
    float* __restrict__ out)
{
    __shared__ float red[4][64];
    const int lane = threadIdx.x & 63;
    const int w    = threadIdx.x >> 6;
    const int b    = blockIdx.x * 64 + lane;

    float acc = 0.0f;
    #pragma unroll 8
    for (int k = w; k < NROWS; k += 4)
        acc += partial[(size_t)k * BATCH + b];
    red[w][lane] = acc;
    __syncthreads();

    if (w == 0) {
        float numer = red[0][lane] + red[1][lane] + red[2][lane] + red[3][lane];

        const float4* xv = reinterpret_cast<const float4*>(x + (size_t)b * NI);
        float4 xa = xv[0], xb4 = xv[1];
        float xr[NI];
        xr[0]=xa.x; xr[1]=xa.y; xr[2]=xa.z; xr[3]=xa.w;
        xr[4]=xb4.x; xr[5]=xb4.y; xr[6]=xb4.z; xr[7]=xb4.w;

        float il2[NM];
        #pragma unroll
        for (int m = 0; m < NM; ++m) {
            float s = sigmas[m];
            il2[m] = IL2C / (s * s);
        }

        float S = 1.0f;     // exact (unscaled) denominator
        float Ksum = 0.0f;  // sum of per-input max exp2-arguments
        #pragma unroll
        for (int j = 0; j < NI; ++j) {
            float am[NM];
            #pragma unroll
            for (int m = 0; m < NM; ++m) {
                float d = xr[j] - centers[j * NM + m];
                am[m] = d * d * il2[m];
            }
            S *= exp2f(am[0]) + exp2f(am[1]) + exp2f(am[2]);
            Ksum += fmaxf(fmaxf(am[0], am[1]), am[2]);
        }

        float scale = exp2f(Ksum);   // <= 1; underflow -> 0 only when out ~ 0
        out[b] = numer * scale / (S + 1e-6f);
    }
}

extern "C" void kernel_launch(void* const* d_in, const int* in_sizes, int n_in,
                              void* d_out, int out_size, void* d_ws, size_t ws_size,
                              hipStream_t stream)
{
    const float* x       = (const float*)d_in[0];
    const float* centers = (const float*)d_in[1];
    const float* sigmas  = (const float*)d_in[2];
    const float* cons    = (const float*)d_in[3];
    float* out           = (float*)d_out;

    float* partial = (float*)d_ws;                                    // 81*8192*4 = 2.65 MB
    u32*   H       = (u32*)((char*)d_ws + (size_t)NROWS * BATCH * 4); // 81*369*4 ≈ 120 KB

    const int prep_total = NROWS * HROW;   // 29889
    sugeno_prep<<<(prep_total + 255) / 256, 256, 0, stream>>>(cons, H);

    dim3 grid1(BATCH / 256, NROWS, 1);
    sugeno_partial<<<grid1, dim3(256, 1, 1), 0, stream>>>(x, centers, sigmas, H, partial);

    sugeno_reduce<<<BATCH / 64, 256, 0, stream>>>(x, centers, sigmas, partial, out);
}

// Round 6
// 32.809 us; speedup vs baseline: 1.0259x; 1.0259x over previous
//
#include <hip/hip_runtime.h>
#include <math.h>

#define BATCH   8192
#define NI      8
#define NM      3
#define NROWS   81     // rH = digits of inputs 0..3
#define NL      81     // rL = digits of inputs 4..7
#define IL2C    (-0.72134752f)  // -0.5*log2(e): mu = exp2(d*d*IL2C/sigma^2)

// partial[rH][b] = sum_{rL} s[b, rH*81+rL] * (xb[b] . cons[rH*81+rL])
// rH comes ONLY from blockIdx.y -> all cons/centers picks are wave-uniform ->
// scalar-pipe s_load; VALU stream is the 9-FMA-per-rule accumulation.
__global__ __launch_bounds__(256) void sugeno_partial(
    const float* __restrict__ x,        // [BATCH][8]
    const float* __restrict__ centers,  // [8][3]
    const float* __restrict__ sigmas,   // [3]
    const float* __restrict__ cons,     // [6561][9]
    float* __restrict__ partial)        // [81][BATCH]
{
    const int b  = blockIdx.x * 256 + threadIdx.x;
    const int rH = blockIdx.y;          // uniform

    const float4* xv = reinterpret_cast<const float4*>(x + (size_t)b * NI);
    float4 xa = xv[0], xb4 = xv[1];
    float xr[NI];
    xr[0]=xa.x; xr[1]=xa.y; xr[2]=xa.z; xr[3]=xa.w;
    xr[4]=xb4.x; xr[5]=xb4.y; xr[6]=xb4.z; xr[7]=xb4.w;

    float il2[NM];
    #pragma unroll
    for (int m = 0; m < NM; ++m) {
        float s = sigmas[m];
        il2[m] = IL2C / (s * s);
    }

    // digits of rH (uniform)
    const int d0 = rH / 27;
    const int d1 = (rH / 9) % 3;
    const int d2 = (rH / 3) % 3;
    const int d3 = rH % 3;

    // ph: only the SELECTED membership per input 0..3 (4 exps; centers/sigma
    // picks are uniform -> scalar loads)
    float dd0 = xr[0] - centers[0 * NM + d0];
    float dd1 = xr[1] - centers[1 * NM + d1];
    float dd2 = xr[2] - centers[2 * NM + d2];
    float dd3 = xr[3] - centers[3 * NM + d3];
    float ph = exp2f(dd0 * dd0 * il2[d0]) * exp2f(dd1 * dd1 * il2[d1])
             * exp2f(dd2 * dd2 * il2[d2]) * exp2f(dd3 * dd3 * il2[d3]);

    // memberships for inputs 4..7 (12 exps)
    float mu4[NM], mu5[NM], mu6[NM], mu7[NM];
    #pragma unroll
    for (int m = 0; m < NM; ++m) {
        float e4 = xr[4] - centers[4 * NM + m];
        float e5 = xr[5] - centers[5 * NM + m];
        float e6 = xr[6] - centers[6 * NM + m];
        float e7 = xr[7] - centers[7 * NM + m];
        mu4[m] = exp2f(e4 * e4 * il2[m]);
        mu5[m] = exp2f(e5 * e5 * il2[m]);
        mu6[m] = exp2f(e6 * e6 * il2[m]);
        mu7[m] = exp2f(e7 * e7 * il2[m]);
    }

    const float* __restrict__ crow = cons + (size_t)rH * NL * 9;

    float V[9];
    #pragma unroll
    for (int i = 0; i < 9; ++i) V[i] = 0.0f;

    // fully unrolled: s = ph*mu4*mu5*mu6*mu7 via nested products (minimal
    // live values), then 9 FMAs against uniform (SGPR) consequents.
    #pragma unroll
    for (int m4 = 0; m4 < 3; ++m4) {
        const float p4 = ph * mu4[m4];
        #pragma unroll
        for (int m5 = 0; m5 < 3; ++m5) {
            const float p5 = p4 * mu5[m5];
            #pragma unroll
            for (int m6 = 0; m6 < 3; ++m6) {
                const float p6 = p5 * mu6[m6];
                #pragma unroll
                for (int m7 = 0; m7 < 3; ++m7) {
                    const float s = p6 * mu7[m7];
                    const float* cr = crow + (size_t)((((m4*3+m5)*3+m6)*3)+m7) * 9;
                    #pragma unroll
                    for (int i = 0; i < 9; ++i) V[i] += s * cr[i];
                }
            }
        }
    }

    const float numer = V[0]*xr[0] + V[1]*xr[1] + V[2]*xr[2] + V[3]*xr[3]
                      + V[4]*xr[4] + V[5]*xr[5] + V[6]*xr[6] + V[7]*xr[7]
                      + V[8];
    partial[(size_t)rH * BATCH + b] = numer;
}

// out[b] = (sum_rH partial[rH][b]) / (prod_j sum_m mu[b,j,m] + 1e-6)
__global__ __launch_bounds__(256) void sugeno_reduce(
    const float* __restrict__ x,
    const float* __restrict__ centers,
    const float* __restrict__ sigmas,
    const float* __restrict__ partial,
    float* __restrict__ out)
{
    __shared__ float red[4][64];
    const int lane = threadIdx.x & 63;
    const int w    = threadIdx.x >> 6;
    const int b    = blockIdx.x * 64 + lane;

    float acc = 0.0f;
    #pragma unroll 7
    for (int k = w; k < NROWS; k += 4)
        acc += partial[(size_t)k * BATCH + b];
    red[w][lane] = acc;
    __syncthreads();

    if (w == 0) {
        float numer = red[0][lane] + red[1][lane] + red[2][lane] + red[3][lane];

        const float4* xv = reinterpret_cast<const float4*>(x + (size_t)b * NI);
        float4 xa = xv[0], xb4 = xv[1];
        float xr[NI];
        xr[0]=xa.x; xr[1]=xa.y; xr[2]=xa.z; xr[3]=xa.w;
        xr[4]=xb4.x; xr[5]=xb4.y; xr[6]=xb4.z; xr[7]=xb4.w;

        float il2[NM];
        #pragma unroll
        for (int m = 0; m < NM; ++m) {
            float s = sigmas[m];
            il2[m] = IL2C / (s * s);
        }

        float denom = 1.0f;
        #pragma unroll
        for (int j = 0; j < NI; ++j) {
            float srow = 0.0f;
            #pragma unroll
            for (int m = 0; m < NM; ++m) {
                float d = xr[j] - centers[j * NM + m];
                srow += exp2f(d * d * il2[m]);
            }
            denom *= srow;
        }
        out[b] = numer / (denom + 1e-6f);
    }
}

extern "C" void kernel_launch(void* const* d_in, const int* in_sizes, int n_in,
                              void* d_out, int out_size, void* d_ws, size_t ws_size,
                              hipStream_t stream)
{
    const float* x       = (const float*)d_in[0];
    const float* centers = (const float*)d_in[1];
    const float* sigmas  = (const float*)d_in[2];
    const float* cons    = (const float*)d_in[3];
    float* out           = (float*)d_out;
    float* partial       = (float*)d_ws;   // 81*8192*4 = 2.65 MB

    dim3 grid1(BATCH / 256, NROWS, 1);
    sugeno_partial<<<grid1, dim3(256, 1, 1), 0, stream>>>(x, centers, sigmas, cons, partial);

    sugeno_reduce<<<BATCH / 64, 256, 0, stream>>>(x, centers, sigmas, partial, out);
}

// Round 7
// 29.309 us; speedup vs baseline: 1.1484x; 1.1194x over previous
//
#include <hip/hip_runtime.h>
#include <math.h>
#include <stdint.h>

#define BATCH 8192
#define NI    8
#define NM    3
#define NT    243             // K-steps; step t carries digits d0..d4, 27 rules (+5 zero pads)
#define IL2C  (-0.72134752f)  // -0.5*log2(e): mu = exp2(d*d*IL2C/sigma^2)

typedef uint32_t u32;
typedef __fp16 h2    __attribute__((ext_vector_type(2)));
typedef __fp16 f16x8 __attribute__((ext_vector_type(8)));
typedef float  f32x4 __attribute__((ext_vector_type(4)));
typedef u32    u32x4 __attribute__((ext_vector_type(4)));

__device__ __forceinline__ u32 pack2(float a, float b) {
    h2 p = __builtin_amdgcn_cvt_pkrtz(a, b);
    return __builtin_bit_cast(u32, p);
}
// runtime-index select over a register triple (compiles to cndmask, no scratch)
__device__ __forceinline__ float sel3(const float* v, int i) {
    return (i == 0) ? v[0] : ((i == 1) ? v[1] : v[2]);
}

// Bpack[t*64 + lane] = 4 u32 = 8 f16: slot j -> k = (lane>>4)*8 + j,
// value = (k<27 && n<9) ? c[t*27 + k][n] : 0, n = lane&15.
// Same (lane,j)->rule map as the A-side generator => consistent contraction.
__global__ __launch_bounds__(256) void sugeno_prep(
    const float* __restrict__ cons,   // [6561][9]
    u32* __restrict__ Bpack)
{
    int idx = blockIdx.x * 256 + threadIdx.x;
    if (idx >= NT * 64) return;
    int t  = idx >> 6;
    int l  = idx & 63;
    int n  = l & 15;
    int kb = (l >> 4) * 8;
    u32 w[4];
    #pragma unroll
    for (int p = 0; p < 4; ++p) {
        int k0 = kb + 2 * p, k1 = k0 + 1;
        float f0 = (k0 < 27 && n < 9) ? cons[(size_t)(t * 27 + k0) * 9 + n] : 0.0f;
        float f1 = (k1 < 27 && n < 9) ? cons[(size_t)(t * 27 + k1) * 9 + n] : 0.0f;
        w[p] = pack2(f0, f1);
    }
    u32x4 ww; ww[0] = w[0]; ww[1] = w[1]; ww[2] = w[2]; ww[3] = w[3];
    ((u32x4*)Bpack)[idx] = ww;
}

// One block = one 16-batch tile; 4 waves = 4 K-splits (60/60/60/63 steps).
// A on the fly: s'[b,r] = U(t) * L[k], U = prod mu'(inputs 0..4 digits of t),
// L = prod mu'(inputs 5..7 digits of k) fixed per lane. mu' normalized so max=1.
__global__ __launch_bounds__(256) void sugeno_main(
    const float* __restrict__ x,        // [BATCH][8]
    const float* __restrict__ centers,  // [8][3]
    const float* __restrict__ sigmas,   // [3]
    const u32*   __restrict__ Bpack,    // [NT*64] u32x4
    float* __restrict__ out)            // [BATCH]
{
    __shared__ float Wred[4][256];
    const int tid  = threadIdx.x;
    const int l    = tid & 63;
    const int wv   = tid >> 6;
    const int tile = blockIdx.x;
    const int brow = tile * 16 + (l & 15);   // A-row this lane feeds

    const float4* xv = (const float4*)(x + (size_t)brow * NI);
    float4 x0 = xv[0], x1 = xv[1];
    float xr[NI] = {x0.x, x0.y, x0.z, x0.w, x1.x, x1.y, x1.z, x1.w};

    float il2[NM];
    #pragma unroll
    for (int m = 0; m < NM; ++m) {
        float s = sigmas[m];
        il2[m] = IL2C / (s * s);
    }

    // normalized membership tables mA[j][m] = exp2(a_jm - max_m a_jm) in (0,1]
    float mA[NI][NM];
    #pragma unroll
    for (int j = 0; j < NI; ++j) {
        float a0, a1, a2;
        {
            float d0 = xr[j] - centers[j * NM + 0];
            float d1 = xr[j] - centers[j * NM + 1];
            float d2 = xr[j] - centers[j * NM + 2];
            a0 = d0 * d0 * il2[0];
            a1 = d1 * d1 * il2[1];
            a2 = d2 * d2 * il2[2];
        }
        float Kj = fmaxf(fmaxf(a0, a1), a2);
        mA[j][0] = exp2f(a0 - Kj);
        mA[j][1] = exp2f(a1 - Kj);
        mA[j][2] = exp2f(a2 - Kj);
    }

    // fixed per-lane low-digit products L[j] for k = kb + j
    const int kb = (l >> 4) * 8;
    float L[8];
    #pragma unroll
    for (int j = 0; j < 8; ++j) {
        int k = kb + j;
        if (k < 27)
            L[j] = sel3(mA[5], k / 9) * sel3(mA[6], (k % 9) / 3) * sel3(mA[7], k % 3);
        else
            L[j] = 0.0f;
    }

    // K-split: t0 multiple of 3 so the d4 phase is compile-time in the unroll
    const int t0     = wv * 60;                 // 0,60,120,180
    const int ngroup = (wv == 3) ? 21 : 20;     // 243 = 60+60+60+63 steps

    int g3 = t0 / 3;
    int d3 = g3 % 3, d2 = (g3 / 3) % 3, d1 = (g3 / 9) % 3, d0 = g3 / 27;
    float P3 = sel3(mA[0], d0) * sel3(mA[1], d1) * sel3(mA[2], d2) * sel3(mA[3], d3);

    const u32x4* bp = (const u32x4*)Bpack + (size_t)t0 * 64 + l;

    f32x4 acc = {0.0f, 0.0f, 0.0f, 0.0f};

    for (int g = 0; g < ngroup; ++g) {
        #pragma unroll
        for (int ph = 0; ph < 3; ++ph) {        // d4 = ph (compile-time)
            float U = P3 * mA[4][ph];
            u32x4 aw;
            aw[0] = pack2(U * L[0], U * L[1]);
            aw[1] = pack2(U * L[2], U * L[3]);
            aw[2] = pack2(U * L[4], U * L[5]);
            aw[3] = pack2(U * L[6], U * L[7]);
            u32x4 bw = bp[(g * 3 + ph) * 64];
            acc = __builtin_amdgcn_mfma_f32_16x16x32_f16(
                      __builtin_bit_cast(f16x8, aw),
                      __builtin_bit_cast(f16x8, bw),
                      acc, 0, 0, 0);
        }
        if (++d3 == 3) { d3 = 0; if (++d2 == 3) { d2 = 0; if (++d1 == 3) { d1 = 0; ++d0; } } }
        P3 = sel3(mA[0], d0) * sel3(mA[1], d1) * sel3(mA[2], d2) * sel3(mA[3], d3);
    }

    // C/D layout (m89-verified): col = lane&15 (n), row = (lane>>4)*4 + reg (batch-local)
    {
        const int col = l & 15, rgrp = l >> 4;
        #pragma unroll
        for (int r = 0; r < 4; ++r)
            Wred[wv][(rgrp * 4 + r) * 16 + col] = acc[r];
    }
    __syncthreads();

    // combine K-splits + numer dot + denominator
    const int row = tid >> 4, cc = tid & 15;
    float Wsum = Wred[0][tid] + Wred[1][tid] + Wred[2][tid] + Wred[3][tid];
    const int bb = tile * 16 + row;
    float xbv = (cc < 8) ? x[(size_t)bb * NI + cc] : (cc == 8 ? 1.0f : 0.0f);
    float p = Wsum * xbv;
    p += __shfl_xor(p, 1);
    p += __shfl_xor(p, 2);
    p += __shfl_xor(p, 4);
    p += __shfl_xor(p, 8);

    if (cc == 0) {
        const float4* yv = (const float4*)(x + (size_t)bb * NI);
        float4 y0 = yv[0], y1 = yv[1];
        float yr[NI] = {y0.x, y0.y, y0.z, y0.w, y1.x, y1.y, y1.z, y1.w};
        float S = 1.0f, Ksum = 0.0f;
        #pragma unroll
        for (int j = 0; j < NI; ++j) {
            float e0 = yr[j] - centers[j * NM + 0];
            float e1 = yr[j] - centers[j * NM + 1];
            float e2 = yr[j] - centers[j * NM + 2];
            float a0 = e0 * e0 * il2[0];
            float a1 = e1 * e1 * il2[1];
            float a2 = e2 * e2 * il2[2];
            S *= exp2f(a0) + exp2f(a1) + exp2f(a2);
            Ksum += fmaxf(fmaxf(a0, a1), a2);
        }
        out[bb] = p * exp2f(Ksum) / (S + 1e-6f);
    }
}

extern "C" void kernel_launch(void* const* d_in, const int* in_sizes, int n_in,
                              void* d_out, int out_size, void* d_ws, size_t ws_size,
                              hipStream_t stream)
{
    const float* x       = (const float*)d_in[0];
    const float* centers = (const float*)d_in[1];
    const float* sigmas  = (const float*)d_in[2];
    const float* cons    = (const float*)d_in[3];
    float* out           = (float*)d_out;
    u32*   Bpack         = (u32*)d_ws;   // NT*64*16 B = 249 KB

    sugeno_prep<<<(NT * 64 + 255) / 256, 256, 0, stream>>>(cons, Bpack);

    sugeno_main<<<BATCH / 16, 256, 0, stream>>>(x, centers, sigmas, Bpack, out);
}

// Round 8
// 26.037 us; speedup vs baseline: 1.2927x; 1.1257x over previous
//
#include <hip/hip_runtime.h>
#include <math.h>
#include <stdint.h>

#define BATCH 8192
#define NI    8
#define NM    3
#define NT    243             // K-steps; step t = digits d0..d4, 27 rules (+5 zero pads)
#define IL2C  (-0.72134752f)  // -0.5*log2(e): mu = exp2(d*d*IL2C/sigma^2)

typedef uint32_t u32;
typedef __fp16 h2    __attribute__((ext_vector_type(2)));
typedef __fp16 f16x8 __attribute__((ext_vector_type(8)));
typedef float  f32x4 __attribute__((ext_vector_type(4)));
typedef u32    u32x4 __attribute__((ext_vector_type(4)));

__device__ __forceinline__ u32 pack2(float a, float b) {
    h2 p = __builtin_amdgcn_cvt_pkrtz(a, b);
    return __builtin_bit_cast(u32, p);
}
__device__ __forceinline__ float sel3(const float* v, int i) {
    return (i == 0) ? v[0] : ((i == 1) ? v[1] : v[2]);
}

// Bpack[t*64 + lane] = 4 u32 = 8 f16: slot j -> k = (lane>>4)*8 + j,
// value = (k<27 && n<9) ? c[t*27 + k][n] : 0, n = lane&15.
// Same (lane,slot)->k map as the A generator (R7-verified consistent).
__global__ __launch_bounds__(256) void sugeno_prep(
    const float* __restrict__ cons,   // [6561][9]
    u32* __restrict__ Bpack)
{
    int idx = blockIdx.x * 256 + threadIdx.x;
    if (idx >= NT * 64) return;
    int t  = idx >> 6;
    int l  = idx & 63;
    int n  = l & 15;
    int kb = (l >> 4) * 8;
    u32 w[4];
    #pragma unroll
    for (int p = 0; p < 4; ++p) {
        int k0 = kb + 2 * p, k1 = k0 + 1;
        float f0 = (k0 < 27 && n < 9) ? cons[(size_t)(t * 27 + k0) * 9 + n] : 0.0f;
        float f1 = (k1 < 27 && n < 9) ? cons[(size_t)(t * 27 + k1) * 9 + n] : 0.0f;
        w[p] = pack2(f0, f1);
    }
    u32x4 ww; ww[0] = w[0]; ww[1] = w[1]; ww[2] = w[2]; ww[3] = w[3];
    ((u32x4*)Bpack)[idx] = ww;
}

// One block = one 16-batch tile; 8 waves = 8 K-splits (30,...,30,33 steps).
// A on the fly: s'[b,r] = U(t) * L[k]; U = prod mu'(digits of t, inputs 0..4),
// L fixed per lane (inputs 5..7), pre-packed f16; A = pk_mul(L, U).
__global__ __launch_bounds__(512, 4) void sugeno_main(
    const float* __restrict__ x,        // [BATCH][8]
    const float* __restrict__ centers,  // [8][3]
    const float* __restrict__ sigmas,   // [3]
    const u32*   __restrict__ Bpack,    // [NT*64] u32x4
    float* __restrict__ out)            // [BATCH]
{
    __shared__ float Wred[8][256];
    const int tid  = threadIdx.x;
    const int l    = tid & 63;
    const int wv   = tid >> 6;          // 0..7
    const int tile = blockIdx.x;
    const int brow = tile * 16 + (l & 15);

    const float4* xv = (const float4*)(x + (size_t)brow * NI);
    float4 x0 = xv[0], x1 = xv[1];
    float xr[NI] = {x0.x, x0.y, x0.z, x0.w, x1.x, x1.y, x1.z, x1.w};

    float il2[NM];
    #pragma unroll
    for (int m = 0; m < NM; ++m) {
        float s = sigmas[m];
        il2[m] = IL2C / (s * s);
    }

    // normalized memberships mA[j][m] = exp2(a_jm - max_m a_jm) in (0,1]
    float mA[NI][NM];
    #pragma unroll
    for (int j = 0; j < NI; ++j) {
        float d0 = xr[j] - centers[j * NM + 0];
        float d1 = xr[j] - centers[j * NM + 1];
        float d2 = xr[j] - centers[j * NM + 2];
        float a0 = d0 * d0 * il2[0];
        float a1 = d1 * d1 * il2[1];
        float a2 = d2 * d2 * il2[2];
        float Kj = fmaxf(fmaxf(a0, a1), a2);
        mA[j][0] = exp2f(a0 - Kj);
        mA[j][1] = exp2f(a1 - Kj);
        mA[j][2] = exp2f(a2 - Kj);
    }

    // fixed per-lane low-digit products, packed f16 pairs: Lp[i] = (L[2i], L[2i+1])
    const int kb = (l >> 4) * 8;
    u32 Lp[4];
    #pragma unroll
    for (int i = 0; i < 4; ++i) {
        float lv[2];
        #pragma unroll
        for (int h = 0; h < 2; ++h) {
            int k = kb + 2 * i + h;
            lv[h] = (k < 27)
                  ? sel3(mA[5], k / 9) * sel3(mA[6], (k % 9) / 3) * sel3(mA[7], k % 3)
                  : 0.0f;
        }
        Lp[i] = pack2(lv[0], lv[1]);
    }

    // K-split: wave wv takes t0 = wv*30 (multiple of 3), 10 groups (wv7: 11)
    const int t0     = wv * 30;
    const int ngroup = (wv == 7) ? 11 : 10;

    int g3 = t0 / 3;
    int d3 = g3 % 3, d2 = (g3 / 3) % 3, d1 = (g3 / 9) % 3, d0 = g3 / 27;
    float P3 = sel3(mA[0], d0) * sel3(mA[1], d1) * sel3(mA[2], d2) * sel3(mA[3], d3);

    const u32x4* bp = (const u32x4*)Bpack + (size_t)t0 * 64 + l;

    f32x4 acc = {0.0f, 0.0f, 0.0f, 0.0f};

    // double-buffered B: prefetch group g+1 while computing group g
    u32x4 c0 = bp[0], c1 = bp[64], c2 = bp[128];
    for (int g = 0; g < ngroup; ++g) {
        u32x4 n0, n1, n2;
        if (g + 1 < ngroup) {
            const u32x4* nb = bp + (size_t)(g + 1) * 192;
            n0 = nb[0]; n1 = nb[64]; n2 = nb[128];
        }
        #pragma unroll
        for (int ph = 0; ph < 3; ++ph) {        // d4 = ph (compile-time)
            float U = P3 * mA[4][ph];
            u32 uu = pack2(U, U);
            h2 uh = __builtin_bit_cast(h2, uu);
            u32x4 aw;
            #pragma unroll
            for (int i = 0; i < 4; ++i) {
                h2 prod = __builtin_bit_cast(h2, Lp[i]) * uh;   // v_pk_mul_f16
                aw[i] = __builtin_bit_cast(u32, prod);
            }
            u32x4 bw = (ph == 0) ? c0 : (ph == 1) ? c1 : c2;
            acc = __builtin_amdgcn_mfma_f32_16x16x32_f16(
                      __builtin_bit_cast(f16x8, aw),
                      __builtin_bit_cast(f16x8, bw),
                      acc, 0, 0, 0);
        }
        c0 = n0; c1 = n1; c2 = n2;
        if (++d3 == 3) { d3 = 0; if (++d2 == 3) { d2 = 0; if (++d1 == 3) { d1 = 0; ++d0; } } }
        P3 = sel3(mA[0], d0) * sel3(mA[1], d1) * sel3(mA[2], d2) * sel3(mA[3], d3);
    }

    // C/D layout (m89-verified): col = lane&15, row = (lane>>4)*4 + reg
    {
        const int col = l & 15, rgrp = l >> 4;
        #pragma unroll
        for (int r = 0; r < 4; ++r)
            Wred[wv][(rgrp * 4 + r) * 16 + col] = acc[r];
    }
    __syncthreads();

    if (tid < 256) {
        const int row = tid >> 4, cc = tid & 15;
        float Wsum = 0.0f;
        #pragma unroll
        for (int w = 0; w < 8; ++w) Wsum += Wred[w][tid];

        const int bb = tile * 16 + row;
        float xbv = (cc < 8) ? x[(size_t)bb * NI + cc] : (cc == 8 ? 1.0f : 0.0f);
        float p = Wsum * xbv;
        p += __shfl_xor(p, 1);
        p += __shfl_xor(p, 2);
        p += __shfl_xor(p, 4);
        p += __shfl_xor(p, 8);

        if (cc == 0) {
            const float4* yv = (const float4*)(x + (size_t)bb * NI);
            float4 y0 = yv[0], y1 = yv[1];
            float yr[NI] = {y0.x, y0.y, y0.z, y0.w, y1.x, y1.y, y1.z, y1.w};
            float S = 1.0f, Ksum = 0.0f;
            #pragma unroll
            for (int j = 0; j < NI; ++j) {
                float e0 = yr[j] - centers[j * NM + 0];
                float e1 = yr[j] - centers[j * NM + 1];
                float e2 = yr[j] - centers[j * NM + 2];
                float a0 = e0 * e0 * il2[0];
                float a1 = e1 * e1 * il2[1];
                float a2 = e2 * e2 * il2[2];
                S *= exp2f(a0) + exp2f(a1) + exp2f(a2);
                Ksum += fmaxf(fmaxf(a0, a1), a2);
            }
            out[bb] = p * exp2f(Ksum) / (S + 1e-6f);
        }
    }
}

extern "C" void kernel_launch(void* const* d_in, const int* in_sizes, int n_in,
                              void* d_out, int out_size, void* d_ws, size_t ws_size,
                              hipStream_t stream)
{
    const float* x       = (const float*)d_in[0];
    const float* centers = (const float*)d_in[1];
    const float* sigmas  = (const float*)d_in[2];
    const float* cons    = (const float*)d_in[3];
    float* out           = (float*)d_out;
    u32*   Bpack         = (u32*)d_ws;   // NT*64*16 B = 249 KB

    sugeno_prep<<<(NT * 64 + 255) / 256, 256, 0, stream>>>(cons, Bpack);

    sugeno_main<<<BATCH / 16, 512, 0, stream>>>(x, centers, sigmas, Bpack, out);
}